// Round 1
// baseline (29.693 us; speedup 1.0000x reference)
//
#include <hip/hip_runtime.h>

// OverlapLoss_intra: B=64, S=256. Odd-sliced boxes (8192 of them), per-batch
// last-occurrence of each id in [0,128), pair all distinct present ids that
// share a parent (parent taken at the id's last occurrence), sum IoU
// (intersection / min-area) of the corresponding boxes.

#define HALF_MAX 128

__global__ __launch_bounds__(128)
void overlap_loss_kernel(const float* __restrict__ pred_boxes,
                         const int* __restrict__ idv_arr,
                         const int* __restrict__ parent_arr,
                         float* __restrict__ out,
                         int S) {
    const int b = blockIdx.x;
    const int t = threadIdx.x;        // 0..127
    const int half = S >> 1;          // 128

    __shared__ int   s_last[HALF_MAX];
    __shared__ int   s_par[HALF_MAX];
    __shared__ float s_x0[HALF_MAX], s_y0[HALF_MAX], s_x1[HALF_MAX], s_y1[HALF_MAX];

    s_last[t] = -1;
    __syncthreads();

    // Phase 1: last occurrence of each id among odd slots of row b.
    {
        int idv = idv_arr[b * S + 2 * t + 1];
        if (idv >= 0 && idv < half) atomicMax(&s_last[idv], t);
    }
    __syncthreads();

    // Phase 2: per unique id t, load parent + box at last occurrence.
    int lg = s_last[t];
    int p = -1;
    if (lg >= 0) {
        int flat = b * S + 2 * lg + 1;
        p = parent_arr[flat];
        const float* bx = pred_boxes + (size_t)flat * 4;
        float xc = bx[0] * 1440.0f;
        float yc = bx[1] * 2560.0f;
        float w  = bx[2] * 1440.0f;
        float h  = bx[3] * 2560.0f;
        s_x0[t] = xc - 0.5f * w;
        s_y0[t] = yc - 0.5f * h;
        s_x1[t] = xc + 0.5f * w;
        s_y1[t] = yc + 0.5f * h;
    }
    s_par[t] = p;
    __syncthreads();

    // Phase 3: pair id t with every id g > t sharing the same parent.
    float sum = 0.0f;
    if (p >= 0) {
        const float ax0 = s_x0[t], ay0 = s_y0[t], ax1 = s_x1[t], ay1 = s_y1[t];
        const float a1 = (ax1 - ax0) * (ay1 - ay0);
        for (int g = t + 1; g < half; ++g) {
            if (s_par[g] == p) {
                float xl = fmaxf(ax0, s_x0[g]);
                float yt = fmaxf(ay0, s_y0[g]);
                float xr = fminf(ax1, s_x1[g]);
                float yb = fminf(ay1, s_y1[g]);
                if (xr >= xl && yb >= yt) {
                    float a2 = (s_x1[g] - s_x0[g]) * (s_y1[g] - s_y0[g]);
                    sum += (xr - xl) * (yb - yt) / fminf(a1, a2);
                }
            }
        }
    }

    // Reduce across the 2 waves (wave = 64 lanes on gfx950).
    for (int off = 32; off > 0; off >>= 1)
        sum += __shfl_down(sum, off, 64);
    __shared__ float wsum[2];
    if ((t & 63) == 0) wsum[t >> 6] = sum;
    __syncthreads();
    if (t == 0) atomicAdd(out, wsum[0] + wsum[1]);
}

extern "C" void kernel_launch(void* const* d_in, const int* in_sizes, int n_in,
                              void* d_out, int out_size, void* d_ws, size_t ws_size,
                              hipStream_t stream) {
    const float* pred_boxes = (const float*)d_in[0];  // [64,256,4] f32
    const int*   id_        = (const int*)d_in[1];    // [64,256] i32
    const int*   parent_id  = (const int*)d_in[2];    // [64,256] i32
    // d_in[3] = type_id, unused by the reference computation.

    const int BS = in_sizes[1];      // B*S = 16384
    const int S  = 256;
    const int B  = BS / S;           // 64

    float* out = (float*)d_out;
    hipMemsetAsync(out, 0, sizeof(float), stream);
    overlap_loss_kernel<<<B, 128, 0, stream>>>(pred_boxes, id_, parent_id, out, S);
}